// Round 4
// baseline (453.908 us; speedup 1.0000x reference)
//
#include <hip/hip_runtime.h>
#include <hip/hip_bf16.h>
#include <cstdint>

// MHA forward: x(4,2048,1024) f32 -> out(4,2048,1024) f32
// Pipeline: convert/transposes -> QKV gemm (bf16 MFMA) -> flash attn -> out gemm.
// R3: attn gets double-buffered K/V + counted vmcnt (T3/T4 2-phase) + heavy-first qt.
// R4: identical resubmit (R3 never ran — GPU unavailable).

typedef __bf16 bf16;
typedef bf16 bf16x8 __attribute__((ext_vector_type(8)));
typedef bf16 bf16x4 __attribute__((ext_vector_type(4)));
typedef float f32x4 __attribute__((ext_vector_type(4)));

#define B_    4
#define T_    2048
#define D_    1024
#define H_    16
#define HD_   64
#define NTOK  8192
// combined score scale: (1/sqrt(HD)) * log2(e); softmax runs in base-2 domain
#define SCL   0.1803368801111204f

__device__ __forceinline__ void gload16(const void* g, void* lds) {
  __builtin_amdgcn_global_load_lds((__attribute__((address_space(1))) void*)g,
                                   (__attribute__((address_space(3))) void*)lds,
                                   16, 0, 0);
}

// ---------------------------------------------------------------- converts --
__global__ void convert_x(const float* __restrict__ x, bf16* __restrict__ xb) {
  const float4* xv = (const float4*)x;
  int stride = gridDim.x * blockDim.x;
  for (int idx = blockIdx.x * blockDim.x + threadIdx.x; idx < (NTOK * D_) / 4; idx += stride) {
    float4 v = xv[idx];
    bf16x4 o = { (bf16)v.x, (bf16)v.y, (bf16)v.z, (bf16)v.w };
    *(bf16x4*)(xb + (size_t)idx * 4) = o;
  }
}

// W[k][n] f32 -> Wt[n][k] bf16, 4 matrices selected by blockIdx.z
__global__ void wconv(const float* __restrict__ w0, const float* __restrict__ w1,
                      const float* __restrict__ w2, const float* __restrict__ w3,
                      bf16* __restrict__ wt) {
  __shared__ float tile[32][33];
  int z = blockIdx.z;
  const float* W = (z == 0) ? w0 : (z == 1) ? w1 : (z == 2) ? w2 : w3;
  int bx = blockIdx.x, by = blockIdx.y;
  int tx = threadIdx.x, ty = threadIdx.y;
#pragma unroll
  for (int r = 0; r < 32; r += 8)
    tile[ty + r][tx] = W[(size_t)(by * 32 + ty + r) * D_ + bx * 32 + tx];
  __syncthreads();
  bf16* dst = wt + (size_t)z * D_ * D_;
#pragma unroll
  for (int r = 0; r < 32; r += 8)
    dst[(size_t)(bx * 32 + ty + r) * D_ + by * 32 + tx] = (bf16)tile[tx][ty + r];
}

// ------------------------------------------------------------------- GEMM ---
// C(M=8192 x N=1024) = A(row-major, K=1024) * Wt^T   (Wt is [n][k])
// MODE 0: QKV — z selects weight slice & output; Q/K -> (bh,t,hd) bf16, V -> (bh,hd,t) bf16
// MODE 2: out-proj — fp32 output + bias
template<int MODE>
__global__ __launch_bounds__(256) void gemm128(const bf16* __restrict__ A,
                                               const bf16* __restrict__ Wt,
                                               bf16* __restrict__ outb,
                                               float* __restrict__ outf,
                                               const float* __restrict__ bias) {
  __shared__ __align__(16) bf16 Ash[128 * 32];
  __shared__ __align__(16) bf16 Bsh[128 * 32];
  const int tid = threadIdx.x;
  const int w = tid >> 6, l = tid & 63;
  const int l15 = l & 15, lq = l >> 4;
  const int wr = w >> 1, wc = w & 1;
  const int tm = blockIdx.x, tn = blockIdx.y, z = blockIdx.z;
  const int K = D_;
  const bf16* Bt = Wt + (size_t)z * D_ * D_;

  // staging: 512 16B chunks per tile; chunk i -> row=i>>2, cc=i&3, src chunk cc^((row>>1)&3)
  const bf16* aSrc[2];
  const bf16* bSrc[2];
  uint32_t sLds[2];
#pragma unroll
  for (int c = 0; c < 2; ++c) {
    int i = (w * 2 + c) * 64 + l;
    int row = i >> 2, cc = i & 3;
    int sc = cc ^ ((row >> 1) & 3);
    aSrc[c] = A + (size_t)(tm * 128 + row) * K + sc * 8;
    bSrc[c] = Bt + (size_t)(tn * 128 + row) * K + sc * 8;
    sLds[c] = (uint32_t)(w * 2 + c) * 1024;
  }
  uint32_t aOff[4], bOff[4];
#pragma unroll
  for (int m = 0; m < 4; ++m) {
    int ra = wr * 64 + m * 16 + l15;
    aOff[m] = ra * 64 + ((lq ^ ((ra >> 1) & 3)) << 4);
    int rb = wc * 64 + m * 16 + l15;
    bOff[m] = rb * 64 + ((lq ^ ((rb >> 1) & 3)) << 4);
  }

  f32x4 acc[4][4] = {};
  char* AshB = (char*)Ash;
  char* BshB = (char*)Bsh;

  for (int k0 = 0; k0 < K; k0 += 32) {
    __syncthreads();
#pragma unroll
    for (int c = 0; c < 2; ++c) {
      gload16(aSrc[c], AshB + sLds[c]);
      gload16(bSrc[c], BshB + sLds[c]);
      aSrc[c] += 32;
      bSrc[c] += 32;
    }
    __syncthreads();
    bf16x8 af[4], bw[4];
#pragma unroll
    for (int m = 0; m < 4; ++m) af[m] = *(const bf16x8*)(AshB + aOff[m]);
#pragma unroll
    for (int n = 0; n < 4; ++n) bw[n] = *(const bf16x8*)(BshB + bOff[n]);
#pragma unroll
    for (int m = 0; m < 4; ++m)
#pragma unroll
      for (int n = 0; n < 4; ++n)
        acc[m][n] = __builtin_amdgcn_mfma_f32_16x16x32_bf16(af[m], bw[n], acc[m][n], 0, 0, 0);
  }

#pragma unroll
  for (int m = 0; m < 4; ++m)
#pragma unroll
    for (int n = 0; n < 4; ++n)
#pragma unroll
      for (int j = 0; j < 4; ++j) {
        int r = tm * 128 + wr * 64 + m * 16 + lq * 4 + j;
        int c = tn * 128 + wc * 64 + n * 16 + l15;
        float v = acc[m][n][j];
        if (MODE == 2) {
          outf[(size_t)r * D_ + c] = v + bias[c];
        } else {
          int b = r >> 11, t = r & (T_ - 1), h = c >> 6, hd = c & 63;
          bf16* dst = outb + (size_t)z * NTOK * D_;
          size_t addr;
          if (z < 2) addr = ((size_t)(b * H_ + h) * T_ + t) * HD_ + hd;   // Q,K: (bh,t,hd)
          else       addr = ((size_t)(b * H_ + h) * HD_ + hd) * T_ + t;   // V: (bh,hd,t)
          dst[addr] = (bf16)v;
        }
      }
}

// ------------------------------------------------------------- attention ---
// grid (qt=T/128, bh=64), 256 thr = 4 waves, each wave owns 32 q-rows. KVBLK=64.
// Double-buffered K/V: STAGE(t+1) -> vmcnt(4) -> barrier -> compute(t) -> barrier.
__global__ __launch_bounds__(256) void attn(const bf16* __restrict__ Q,
                                            const bf16* __restrict__ Kg,
                                            const bf16* __restrict__ Vg,
                                            bf16* __restrict__ ctx) {
  __shared__ __align__(16) bf16 Ksh[2][64 * 64];   // [buf][kv][hd], chunk-swizzled
  __shared__ __align__(16) bf16 Vsh[2][64 * 64];   // [buf][hd][kv], chunk-swizzled
  __shared__ __align__(16) bf16 Psh[4 * 32 * 64];  // per-wave [q][kv], swizzled
  const int tid = threadIdx.x;
  const int w = tid >> 6, l = tid & 63;
  const int l15 = l & 15, lq = l >> 4;
  const int qt = (int)(gridDim.x - 1 - blockIdx.x);  // heavy blocks dispatch first
  const int bh = blockIdx.y;
  const int qbase = qt * 128 + w * 32;

  bf16x8 qf[2][2];
#pragma unroll
  for (int m = 0; m < 2; ++m)
#pragma unroll
    for (int ks = 0; ks < 2; ++ks)
      qf[m][ks] = *(const bf16x8*)(Q + ((size_t)bh * T_ + qbase + m * 16 + l15) * HD_ + ks * 32 + lq * 8);
  // force Q into registers now so compiler's waitcnt for qf doesn't drain staged loads
#pragma unroll
  for (int m = 0; m < 2; ++m)
#pragma unroll
    for (int ks = 0; ks < 2; ++ks)
      asm volatile("" : "+v"(qf[m][ks]));

  f32x4 acc_o[2][4] = {};
  float mr[2][4], lr[2][4];
#pragma unroll
  for (int m = 0; m < 2; ++m)
#pragma unroll
    for (int j = 0; j < 4; ++j) { mr[m][j] = -__builtin_inff(); lr[m][j] = 0.f; }

  const bf16* kSrc[2];
  const bf16* vSrc[2];
  uint32_t sLds[2];
#pragma unroll
  for (int c = 0; c < 2; ++c) {
    int i = (w * 2 + c) * 64 + l;
    int row = i >> 3, cc = i & 7;
    int sc = cc ^ (row & 7);
    kSrc[c] = Kg + ((size_t)bh * T_ + row) * HD_ + sc * 8;
    vSrc[c] = Vg + ((size_t)bh * HD_ + row) * T_ + sc * 8;
    sLds[c] = (uint32_t)(w * 2 + c) * 1024;
  }

  char* KshB = (char*)Ksh;
  char* VshB = (char*)Vsh;
  char* PshB = (char*)Psh;
  uint32_t kOff[2][4], pOff[2][2];
#pragma unroll
  for (int ks = 0; ks < 2; ++ks) {
#pragma unroll
    for (int n = 0; n < 4; ++n) {
      int row = n * 16 + l15, c = ks * 4 + lq;
      kOff[ks][n] = row * 128 + ((c ^ (row & 7)) << 4);
    }
#pragma unroll
    for (int m = 0; m < 2; ++m) {
      int row = m * 16 + l15, c = ks * 4 + lq;
      pOff[ks][m] = w * 4096 + row * 128 + ((c ^ (row & 7)) << 4);
    }
  }

  const int kvmax = 2 * qt + 2;

  // prologue: stage tile 0 into buffer 0
#pragma unroll
  for (int c = 0; c < 2; ++c) {
    gload16(kSrc[c], KshB + sLds[c]);
    gload16(vSrc[c], VshB + sLds[c]);
    kSrc[c] += 64 * HD_;
    vSrc[c] += 64;
  }

  for (int kvt = 0; kvt < kvmax; ++kvt) {
    const uint32_t cb = (uint32_t)(kvt & 1) * 8192;  // current buffer byte offset
    const uint32_t nb = cb ^ 8192;                   // next buffer
    const bool pre = (kvt + 1) < kvmax;
    if (pre) {
#pragma unroll
      for (int c = 0; c < 2; ++c) {
        gload16(kSrc[c], KshB + nb + sLds[c]);
        gload16(vSrc[c], VshB + nb + sLds[c]);
        kSrc[c] += 64 * HD_;
        vSrc[c] += 64;
      }
      asm volatile("s_waitcnt vmcnt(4)" ::: "memory");  // current tile's 4 loads done
    } else {
      asm volatile("s_waitcnt vmcnt(0)" ::: "memory");
    }
    __builtin_amdgcn_sched_barrier(0);
    __builtin_amdgcn_s_barrier();
    __builtin_amdgcn_sched_barrier(0);

    // wave-uniform skip: tile entirely above the causal diagonal for this wave
    const bool active = (kvt * 64) <= (qbase + 31);
    if (active) {
      // S = Q K^T
      f32x4 accs[2][4] = {};
      __builtin_amdgcn_s_setprio(1);
#pragma unroll
      for (int ks = 0; ks < 2; ++ks) {
        bf16x8 kf[4];
#pragma unroll
        for (int n = 0; n < 4; ++n) kf[n] = *(const bf16x8*)(KshB + cb + kOff[ks][n]);
#pragma unroll
        for (int m = 0; m < 2; ++m)
#pragma unroll
          for (int n = 0; n < 4; ++n)
            accs[m][n] = __builtin_amdgcn_mfma_f32_16x16x32_bf16(qf[m][ks], kf[n], accs[m][n], 0, 0, 0);
      }
      __builtin_amdgcn_s_setprio(0);

      const bool needmask = (kvt * 64 + 63) > qbase;
#pragma unroll
      for (int m = 0; m < 2; ++m)
#pragma unroll
        for (int n = 0; n < 4; ++n) {
          accs[m][n] *= SCL;  // (1/sqrt(HD))*log2e: softmax in base-2 domain
          if (needmask) {
            int kv = kvt * 64 + n * 16 + l15;
#pragma unroll
            for (int j = 0; j < 4; ++j) {
              int q = qbase + m * 16 + lq * 4 + j;
              if (kv > q) accs[m][n][j] = -__builtin_inff();
            }
          }
        }

      // online softmax (row q's 16 cols live in lanes lq*16+0..15)
#pragma unroll
      for (int m = 0; m < 2; ++m)
#pragma unroll
        for (int j = 0; j < 4; ++j) {
          float v = fmaxf(fmaxf(accs[m][0][j], accs[m][1][j]),
                          fmaxf(accs[m][2][j], accs[m][3][j]));
#pragma unroll
          for (int s = 8; s >= 1; s >>= 1) v = fmaxf(v, __shfl_xor(v, s));
          float mn = fmaxf(mr[m][j], v);
          float r = exp2f(mr[m][j] - mn);
          mr[m][j] = mn;
          float rs = 0.f;
          int rowP = m * 16 + lq * 4 + j;
#pragma unroll
          for (int n = 0; n < 4; ++n) {
            float p = exp2f(accs[m][n][j] - mn);
            rs += p;
            int colP = n * 16 + l15;
            *(bf16*)(PshB + w * 4096 + rowP * 128 +
                     ((((colP >> 3) ^ (rowP & 7)) << 4)) + ((colP & 7) << 1)) = (bf16)p;
          }
#pragma unroll
          for (int s = 8; s >= 1; s >>= 1) rs += __shfl_xor(rs, s);
          lr[m][j] = lr[m][j] * r + rs;
#pragma unroll
          for (int n = 0; n < 4; ++n) acc_o[m][n][j] *= r;
        }

      asm volatile("s_waitcnt lgkmcnt(0)" ::: "memory");
      __builtin_amdgcn_sched_barrier(0);

      // O += P V (P is per-wave private in LDS)
      __builtin_amdgcn_s_setprio(1);
#pragma unroll
      for (int ks = 0; ks < 2; ++ks) {
        bf16x8 pf[2], vf[4];
#pragma unroll
        for (int m = 0; m < 2; ++m) pf[m] = *(const bf16x8*)(PshB + pOff[ks][m]);
#pragma unroll
        for (int n = 0; n < 4; ++n) vf[n] = *(const bf16x8*)(VshB + cb + kOff[ks][n]);
#pragma unroll
        for (int m = 0; m < 2; ++m)
#pragma unroll
          for (int n = 0; n < 4; ++n)
            acc_o[m][n] = __builtin_amdgcn_mfma_f32_16x16x32_bf16(pf[m], vf[n], acc_o[m][n], 0, 0, 0);
      }
      __builtin_amdgcn_s_setprio(0);
    }
    // all waves done reading buf[cb] before next iteration stages into it
    __builtin_amdgcn_s_barrier();
  }

  const int b = bh >> 4, h = bh & 15;
#pragma unroll
  for (int m = 0; m < 2; ++m)
#pragma unroll
    for (int n = 0; n < 4; ++n)
#pragma unroll
      for (int j = 0; j < 4; ++j) {
        int t = qbase + m * 16 + lq * 4 + j;
        int c = h * 64 + n * 16 + l15;
        float v = acc_o[m][n][j] / lr[m][j];
        ctx[((size_t)b * T_ + t) * D_ + c] = (bf16)v;
      }
}

// ----------------------------------------------------------------- launch ---
extern "C" void kernel_launch(void* const* d_in, const int* in_sizes, int n_in,
                              void* d_out, int out_size, void* d_ws, size_t ws_size,
                              hipStream_t stream) {
  const float* x  = (const float*)d_in[0];
  const float* Wq = (const float*)d_in[1];
  const float* Wk = (const float*)d_in[2];
  const float* Wv = (const float*)d_in[3];
  const float* Wo = (const float*)d_in[4];
  const float* bo = (const float*)d_in[5];
  float* out = (float*)d_out;

  bf16* ws  = (bf16*)d_ws;
  bf16* xb  = ws;                                   //  8M elems: x bf16
  bf16* wt  = ws + (size_t)8 * 1024 * 1024;         //  4M elems: Wq^T,Wk^T,Wv^T,Wo^T
  bf16* qkv = ws + (size_t)12 * 1024 * 1024;        // 24M elems: Q, K, Vt
  bf16* ctx = ws + (size_t)36 * 1024 * 1024;        //  8M elems: attn output
  // total 44M bf16 = 88 MB

  convert_x<<<2048, 256, 0, stream>>>(x, xb);
  wconv<<<dim3(32, 32, 4), dim3(32, 8), 0, stream>>>(Wq, Wk, Wv, Wo, wt);
  gemm128<0><<<dim3(64, 8, 3), 256, 0, stream>>>(xb, wt, qkv, nullptr, nullptr);
  attn<<<dim3(16, 64), 256, 0, stream>>>(qkv, qkv + (size_t)8 * 1024 * 1024,
                                         qkv + (size_t)16 * 1024 * 1024, ctx);
  gemm128<2><<<dim3(64, 8, 1), 256, 0, stream>>>(ctx, wt + (size_t)3 * 1024 * 1024,
                                                 nullptr, out, bo);
}

// Round 9
// 304.579 us; speedup vs baseline: 1.4903x; 1.4903x over previous
//
#include <hip/hip_runtime.h>
#include <hip/hip_bf16.h>
#include <cstdint>

// MHA forward: x(4,2048,1024) f32 -> out(4,2048,1024) f32
// Pipeline: convert/transposes -> QKV gemm (bf16 MFMA) -> flash attn -> out gemm.
// R5: attn softmax -> DPP reductions (no LDS shuffles), fused scale into exp2,
//     cheap P-write addressing, paired q-tiles (15-bx, bx) for perfect causal balance.
// R6-R9: identical resubmit (R5-R8 never ran — GPU unavailable).

typedef __bf16 bf16;
typedef bf16 bf16x8 __attribute__((ext_vector_type(8)));
typedef bf16 bf16x4 __attribute__((ext_vector_type(4)));
typedef float f32x4 __attribute__((ext_vector_type(4)));

#define B_    4
#define T_    2048
#define D_    1024
#define H_    16
#define HD_   64
#define NTOK  8192
// score scale folded into exponent: p = exp2(s*SCL - m*SCL); SCL = log2(e)/sqrt(HD)
#define SCL   0.1803368801111204f

#if __has_builtin(__builtin_amdgcn_exp2f)
#define EXP2(x) __builtin_amdgcn_exp2f(x)
#else
#define EXP2(x) exp2f(x)
#endif

__device__ __forceinline__ void gload16(const void* g, void* lds) {
  __builtin_amdgcn_global_load_lds((__attribute__((address_space(1))) void*)g,
                                   (__attribute__((address_space(3))) void*)lds,
                                   16, 0, 0);
}

// DPP 16-lane butterfly reduce steps (rows = aligned 16-lane groups)
template<int CTRL>
__device__ __forceinline__ float dpp_max_step(float x) {
  int xi = __builtin_bit_cast(int, x);
  int yi = __builtin_amdgcn_update_dpp(xi, xi, CTRL, 0xF, 0xF, false);
  return fmaxf(x, __builtin_bit_cast(float, yi));
}
template<int CTRL>
__device__ __forceinline__ float dpp_add_step(float x) {
  int xi = __builtin_bit_cast(int, x);
  int yi = __builtin_amdgcn_update_dpp(xi, xi, CTRL, 0xF, 0xF, false);
  return x + __builtin_bit_cast(float, yi);
}
__device__ __forceinline__ float row16_max(float v) {
  v = dpp_max_step<0xB1>(v);   // quad_perm [1,0,3,2]  (xor 1)
  v = dpp_max_step<0x4E>(v);   // quad_perm [2,3,0,1]  (xor 2)
  v = dpp_max_step<0x141>(v);  // row_half_mirror      (xor 7)
  v = dpp_max_step<0x140>(v);  // row_mirror           (xor 15)
  return v;
}
__device__ __forceinline__ float row16_sum(float v) {
  v = dpp_add_step<0xB1>(v);
  v = dpp_add_step<0x4E>(v);
  v = dpp_add_step<0x141>(v);
  v = dpp_add_step<0x140>(v);
  return v;
}

// ---------------------------------------------------------------- converts --
__global__ void convert_x(const float* __restrict__ x, bf16* __restrict__ xb) {
  const float4* xv = (const float4*)x;
  int stride = gridDim.x * blockDim.x;
  for (int idx = blockIdx.x * blockDim.x + threadIdx.x; idx < (NTOK * D_) / 4; idx += stride) {
    float4 v = xv[idx];
    bf16x4 o = { (bf16)v.x, (bf16)v.y, (bf16)v.z, (bf16)v.w };
    *(bf16x4*)(xb + (size_t)idx * 4) = o;
  }
}

// W[k][n] f32 -> Wt[n][k] bf16, 4 matrices selected by blockIdx.z
__global__ void wconv(const float* __restrict__ w0, const float* __restrict__ w1,
                      const float* __restrict__ w2, const float* __restrict__ w3,
                      bf16* __restrict__ wt) {
  __shared__ float tile[32][33];
  int z = blockIdx.z;
  const float* W = (z == 0) ? w0 : (z == 1) ? w1 : (z == 2) ? w2 : w3;
  int bx = blockIdx.x, by = blockIdx.y;
  int tx = threadIdx.x, ty = threadIdx.y;
#pragma unroll
  for (int r = 0; r < 32; r += 8)
    tile[ty + r][tx] = W[(size_t)(by * 32 + ty + r) * D_ + bx * 32 + tx];
  __syncthreads();
  bf16* dst = wt + (size_t)z * D_ * D_;
#pragma unroll
  for (int r = 0; r < 32; r += 8)
    dst[(size_t)(bx * 32 + ty + r) * D_ + by * 32 + tx] = (bf16)tile[tx][ty + r];
}

// ------------------------------------------------------------------- GEMM ---
// C(M=8192 x N=1024) = A(row-major, K=1024) * Wt^T   (Wt is [n][k])
// MODE 0: QKV — z selects weight slice & output; Q/K -> (bh,t,hd) bf16, V -> (bh,hd,t) bf16
// MODE 2: out-proj — fp32 output + bias
template<int MODE>
__global__ __launch_bounds__(256) void gemm128(const bf16* __restrict__ A,
                                               const bf16* __restrict__ Wt,
                                               bf16* __restrict__ outb,
                                               float* __restrict__ outf,
                                               const float* __restrict__ bias) {
  __shared__ __align__(16) bf16 Ash[128 * 32];
  __shared__ __align__(16) bf16 Bsh[128 * 32];
  const int tid = threadIdx.x;
  const int w = tid >> 6, l = tid & 63;
  const int l15 = l & 15, lq = l >> 4;
  const int wr = w >> 1, wc = w & 1;
  const int tm = blockIdx.x, tn = blockIdx.y, z = blockIdx.z;
  const int K = D_;
  const bf16* Bt = Wt + (size_t)z * D_ * D_;

  const bf16* aSrc[2];
  const bf16* bSrc[2];
  uint32_t sLds[2];
#pragma unroll
  for (int c = 0; c < 2; ++c) {
    int i = (w * 2 + c) * 64 + l;
    int row = i >> 2, cc = i & 3;
    int sc = cc ^ ((row >> 1) & 3);
    aSrc[c] = A + (size_t)(tm * 128 + row) * K + sc * 8;
    bSrc[c] = Bt + (size_t)(tn * 128 + row) * K + sc * 8;
    sLds[c] = (uint32_t)(w * 2 + c) * 1024;
  }
  uint32_t aOff[4], bOff[4];
#pragma unroll
  for (int m = 0; m < 4; ++m) {
    int ra = wr * 64 + m * 16 + l15;
    aOff[m] = ra * 64 + ((lq ^ ((ra >> 1) & 3)) << 4);
    int rb = wc * 64 + m * 16 + l15;
    bOff[m] = rb * 64 + ((lq ^ ((rb >> 1) & 3)) << 4);
  }

  f32x4 acc[4][4] = {};
  char* AshB = (char*)Ash;
  char* BshB = (char*)Bsh;

  for (int k0 = 0; k0 < K; k0 += 32) {
    __syncthreads();
#pragma unroll
    for (int c = 0; c < 2; ++c) {
      gload16(aSrc[c], AshB + sLds[c]);
      gload16(bSrc[c], BshB + sLds[c]);
      aSrc[c] += 32;
      bSrc[c] += 32;
    }
    __syncthreads();
    bf16x8 af[4], bw[4];
#pragma unroll
    for (int m = 0; m < 4; ++m) af[m] = *(const bf16x8*)(AshB + aOff[m]);
#pragma unroll
    for (int n = 0; n < 4; ++n) bw[n] = *(const bf16x8*)(BshB + bOff[n]);
#pragma unroll
    for (int m = 0; m < 4; ++m)
#pragma unroll
      for (int n = 0; n < 4; ++n)
        acc[m][n] = __builtin_amdgcn_mfma_f32_16x16x32_bf16(af[m], bw[n], acc[m][n], 0, 0, 0);
  }

#pragma unroll
  for (int m = 0; m < 4; ++m)
#pragma unroll
    for (int n = 0; n < 4; ++n)
#pragma unroll
      for (int j = 0; j < 4; ++j) {
        int r = tm * 128 + wr * 64 + m * 16 + lq * 4 + j;
        int c = tn * 128 + wc * 64 + n * 16 + l15;
        float v = acc[m][n][j];
        if (MODE == 2) {
          outf[(size_t)r * D_ + c] = v + bias[c];
        } else {
          int b = r >> 11, t = r & (T_ - 1), h = c >> 6, hd = c & 63;
          bf16* dst = outb + (size_t)z * NTOK * D_;
          size_t addr;
          if (z < 2) addr = ((size_t)(b * H_ + h) * T_ + t) * HD_ + hd;   // Q,K: (bh,t,hd)
          else       addr = ((size_t)(b * H_ + h) * HD_ + hd) * T_ + t;   // V: (bh,hd,t)
          dst[addr] = (bf16)v;
        }
      }
}

// ------------------------------------------------------------- attention ---
// grid (8, bh=64), 256 thr = 4 waves. Each block runs TWO q-tiles sequentially:
// qt = 15-bx then qt = bx  -> 34 KV-tiles per block, perfectly balanced.
// Per pass: double-buffered K/V, counted vmcnt, DPP softmax (no LDS shuffles).
__global__ __launch_bounds__(256) void attn(const bf16* __restrict__ Q,
                                            const bf16* __restrict__ Kg,
                                            const bf16* __restrict__ Vg,
                                            bf16* __restrict__ ctx) {
  __shared__ __align__(16) bf16 Ksh[2][64 * 64];   // [buf][kv][hd], chunk-swizzled
  __shared__ __align__(16) bf16 Vsh[2][64 * 64];   // [buf][hd][kv], chunk-swizzled
  __shared__ __align__(16) bf16 Psh[4 * 32 * 64];  // per-wave [q][kv], swizzled
  const int tid = threadIdx.x;
  const int w = tid >> 6, l = tid & 63;
  const int l15 = l & 15, lq = l >> 4;
  const int bx = blockIdx.x, bh = blockIdx.y;

  char* KshB = (char*)Ksh;
  char* VshB = (char*)Vsh;
  char* PshB = (char*)Psh;

  // staging lane->(row, chunk) with source-side swizzle (LDS dest stays linear)
  uint32_t stRow[2], stCol[2], sLds[2];
#pragma unroll
  for (int c = 0; c < 2; ++c) {
    int i = (w * 2 + c) * 64 + l;
    int row = i >> 3, cc = i & 7;
    stRow[c] = row;
    stCol[c] = (cc ^ (row & 7)) * 8;
    sLds[c] = (uint32_t)(w * 2 + c) * 1024;
  }
  uint32_t kOff[2][4], pOff[2][2];
#pragma unroll
  for (int ks = 0; ks < 2; ++ks) {
#pragma unroll
    for (int n = 0; n < 4; ++n) {
      int row = n * 16 + l15, c = ks * 4 + lq;
      kOff[ks][n] = row * 128 + ((c ^ (row & 7)) << 4);
    }
#pragma unroll
    for (int m = 0; m < 2; ++m) {
      int row = m * 16 + l15, c = ks * 4 + lq;
      pOff[ks][m] = w * 4096 + row * 128 + ((c ^ (row & 7)) << 4);
    }
  }
  const uint32_t h16 = (uint32_t)(l & 8) << 1;   // (l15>>3)<<4
  const uint32_t pb0 = w * 4096u + ((uint32_t)(l & 7) << 1);

  const int b = bh >> 4, h = bh & 15;

  for (int pass = 0; pass < 2; ++pass) {
    const int qt = pass ? bx : 15 - bx;
    const int qbase = qt * 128 + w * 32;
    const int kvmax = 2 * qt + 2;

    // Q fragments for this pass
    bf16x8 qf[2][2];
#pragma unroll
    for (int m = 0; m < 2; ++m)
#pragma unroll
      for (int ks = 0; ks < 2; ++ks)
        qf[m][ks] = *(const bf16x8*)(Q + ((size_t)bh * T_ + qbase + m * 16 + l15) * HD_ + ks * 32 + lq * 8);
    // force Q resident now so its waitcnt doesn't fold into the loop
#pragma unroll
    for (int m = 0; m < 2; ++m)
#pragma unroll
      for (int ks = 0; ks < 2; ++ks)
        asm volatile("" : "+v"(qf[m][ks]));

    f32x4 acc_o[2][4] = {};
    float mr[2][4], lr[2][4];
#pragma unroll
    for (int m = 0; m < 2; ++m)
#pragma unroll
      for (int j = 0; j < 4; ++j) { mr[m][j] = -__builtin_inff(); lr[m][j] = 0.f; }

    const bf16* kSrc[2];
    const bf16* vSrc[2];
#pragma unroll
    for (int c = 0; c < 2; ++c) {
      kSrc[c] = Kg + ((size_t)bh * T_ + stRow[c]) * HD_ + stCol[c];
      vSrc[c] = Vg + ((size_t)bh * HD_ + stRow[c]) * T_ + stCol[c];
    }

    // prologue: stage tile 0 into buffer 0
#pragma unroll
    for (int c = 0; c < 2; ++c) {
      gload16(kSrc[c], KshB + sLds[c]);
      gload16(vSrc[c], VshB + sLds[c]);
      kSrc[c] += 64 * HD_;
      vSrc[c] += 64;
    }

    for (int kvt = 0; kvt < kvmax; ++kvt) {
      const uint32_t cb = (uint32_t)(kvt & 1) * 8192;
      const uint32_t nb = cb ^ 8192;
      const bool pre = (kvt + 1) < kvmax;
      if (pre) {
#pragma unroll
        for (int c = 0; c < 2; ++c) {
          gload16(kSrc[c], KshB + nb + sLds[c]);
          gload16(vSrc[c], VshB + nb + sLds[c]);
          kSrc[c] += 64 * HD_;
          vSrc[c] += 64;
        }
        asm volatile("s_waitcnt vmcnt(4)" ::: "memory");
      } else {
        asm volatile("s_waitcnt vmcnt(0)" ::: "memory");
      }
      __builtin_amdgcn_sched_barrier(0);
      __builtin_amdgcn_s_barrier();
      __builtin_amdgcn_sched_barrier(0);

      const bool active = (kvt * 64) <= (qbase + 31);
      if (active) {
        // S = Q K^T (raw scores; scale folded into exp2 args)
        f32x4 accs[2][4] = {};
        __builtin_amdgcn_s_setprio(1);
#pragma unroll
        for (int ks = 0; ks < 2; ++ks) {
          bf16x8 kf[4];
#pragma unroll
          for (int n = 0; n < 4; ++n) kf[n] = *(const bf16x8*)(KshB + cb + kOff[ks][n]);
#pragma unroll
          for (int m = 0; m < 2; ++m)
#pragma unroll
            for (int n = 0; n < 4; ++n)
              accs[m][n] = __builtin_amdgcn_mfma_f32_16x16x32_bf16(qf[m][ks], kf[n], accs[m][n], 0, 0, 0);
        }
        __builtin_amdgcn_s_setprio(0);

        const bool needmask = (kvt * 64 + 63) > qbase;
        if (needmask) {
#pragma unroll
          for (int m = 0; m < 2; ++m)
#pragma unroll
            for (int n = 0; n < 4; ++n) {
              int kv = kvt * 64 + n * 16 + l15;
#pragma unroll
              for (int j = 0; j < 4; ++j) {
                int q = qbase + m * 16 + lq * 4 + j;
                if (kv > q) accs[m][n][j] = -__builtin_inff();
              }
            }
        }

        // online softmax: DPP 16-lane reductions, all-VALU
#pragma unroll
        for (int m = 0; m < 2; ++m)
#pragma unroll
          for (int j = 0; j < 4; ++j) {
            float v = fmaxf(fmaxf(accs[m][0][j], accs[m][1][j]),
                            fmaxf(accs[m][2][j], accs[m][3][j]));
            v = row16_max(v);
            float mn = fmaxf(mr[m][j], v);                 // raw-units running max
            float r = EXP2((mr[m][j] - mn) * SCL);
            mr[m][j] = mn;
            float nm = -mn * SCL;
            int rowP = m * 16 + lq * 4 + j;
            uint32_t pb = pb0 + (uint32_t)rowP * 128u;
            uint32_t px = (uint32_t)(rowP & 7) << 4;
            float rs = 0.f;
#pragma unroll
            for (int n = 0; n < 4; ++n) {
              float p = EXP2(__builtin_fmaf(accs[m][n][j], SCL, nm));
              rs += p;
              *(bf16*)(PshB + pb + (((uint32_t)n * 32u + h16) ^ px)) = (bf16)p;
            }
            rs = row16_sum(rs);
            lr[m][j] = lr[m][j] * r + rs;
#pragma unroll
            for (int n = 0; n < 4; ++n) acc_o[m][n][j] *= r;
          }

        asm volatile("s_waitcnt lgkmcnt(0)" ::: "memory");
        __builtin_amdgcn_sched_barrier(0);

        // O += P V (P per-wave private in LDS)
        __builtin_amdgcn_s_setprio(1);
#pragma unroll
        for (int ks = 0; ks < 2; ++ks) {
          bf16x8 pf[2], vf[4];
#pragma unroll
          for (int m = 0; m < 2; ++m) pf[m] = *(const bf16x8*)(PshB + pOff[ks][m]);
#pragma unroll
          for (int n = 0; n < 4; ++n) vf[n] = *(const bf16x8*)(VshB + cb + kOff[ks][n]);
#pragma unroll
          for (int m = 0; m < 2; ++m)
#pragma unroll
            for (int n = 0; n < 4; ++n)
              acc_o[m][n] = __builtin_amdgcn_mfma_f32_16x16x32_bf16(pf[m], vf[n], acc_o[m][n], 0, 0, 0);
        }
        __builtin_amdgcn_s_setprio(0);
      }
      // all waves done reading buf[cb] before it is re-staged
      __builtin_amdgcn_s_barrier();
    }

    // epilogue for this pass
#pragma unroll
    for (int m = 0; m < 2; ++m)
#pragma unroll
      for (int n = 0; n < 4; ++n)
#pragma unroll
        for (int j = 0; j < 4; ++j) {
          int t = qbase + m * 16 + lq * 4 + j;
          int c = h * 64 + n * 16 + l15;
          float v = acc_o[m][n][j] / lr[m][j];
          ctx[((size_t)b * T_ + t) * D_ + c] = (bf16)v;
        }
  }
}

// ----------------------------------------------------------------- launch ---
extern "C" void kernel_launch(void* const* d_in, const int* in_sizes, int n_in,
                              void* d_out, int out_size, void* d_ws, size_t ws_size,
                              hipStream_t stream) {
  const float* x  = (const float*)d_in[0];
  const float* Wq = (const float*)d_in[1];
  const float* Wk = (const float*)d_in[2];
  const float* Wv = (const float*)d_in[3];
  const float* Wo = (const float*)d_in[4];
  const float* bo = (const float*)d_in[5];
  float* out = (float*)d_out;

  bf16* ws  = (bf16*)d_ws;
  bf16* xb  = ws;                                   //  8M elems: x bf16
  bf16* wt  = ws + (size_t)8 * 1024 * 1024;         //  4M elems: Wq^T,Wk^T,Wv^T,Wo^T
  bf16* qkv = ws + (size_t)12 * 1024 * 1024;        // 24M elems: Q, K, Vt
  bf16* ctx = ws + (size_t)36 * 1024 * 1024;        //  8M elems: attn output
  // total 44M bf16 = 88 MB

  convert_x<<<2048, 256, 0, stream>>>(x, xb);
  wconv<<<dim3(32, 32, 4), dim3(32, 8), 0, stream>>>(Wq, Wk, Wv, Wo, wt);
  gemm128<0><<<dim3(64, 8, 3), 256, 0, stream>>>(xb, wt, qkv, nullptr, nullptr);
  attn<<<dim3(8, 64), 256, 0, stream>>>(qkv, qkv + (size_t)8 * 1024 * 1024,
                                        qkv + (size_t)16 * 1024 * 1024, ctx);
  gemm128<2><<<dim3(64, 8, 1), 256, 0, stream>>>(ctx, wt + (size_t)3 * 1024 * 1024,
                                                 nullptr, out, bo);
}

// Round 11
// 300.193 us; speedup vs baseline: 1.5121x; 1.0146x over previous
//
#include <hip/hip_runtime.h>
#include <hip/hip_bf16.h>
#include <cstdint>

// MHA forward: x(4,2048,1024) f32 -> out(4,2048,1024) f32
// Pipeline: convert/transposes -> QKV gemm (bf16 MFMA) -> flash attn -> out gemm.
// R5 (validated): attn DPP softmax + balanced q-tile pairing -> 121 us.
// R10: gemm128 BK 32->64 (16 K-steps, half the barrier drains), row&7 chunk swizzle.
// R11: identical resubmit (R10 never ran — GPU unavailable).

typedef __bf16 bf16;
typedef bf16 bf16x8 __attribute__((ext_vector_type(8)));
typedef bf16 bf16x4 __attribute__((ext_vector_type(4)));
typedef float f32x4 __attribute__((ext_vector_type(4)));

#define B_    4
#define T_    2048
#define D_    1024
#define H_    16
#define HD_   64
#define NTOK  8192
// score scale folded into exponent: p = exp2(s*SCL - m*SCL); SCL = log2(e)/sqrt(HD)
#define SCL   0.1803368801111204f

#if __has_builtin(__builtin_amdgcn_exp2f)
#define EXP2(x) __builtin_amdgcn_exp2f(x)
#else
#define EXP2(x) exp2f(x)
#endif

__device__ __forceinline__ void gload16(const void* g, void* lds) {
  __builtin_amdgcn_global_load_lds((__attribute__((address_space(1))) void*)g,
                                   (__attribute__((address_space(3))) void*)lds,
                                   16, 0, 0);
}

// DPP 16-lane butterfly reduce steps (rows = aligned 16-lane groups)
template<int CTRL>
__device__ __forceinline__ float dpp_max_step(float x) {
  int xi = __builtin_bit_cast(int, x);
  int yi = __builtin_amdgcn_update_dpp(xi, xi, CTRL, 0xF, 0xF, false);
  return fmaxf(x, __builtin_bit_cast(float, yi));
}
template<int CTRL>
__device__ __forceinline__ float dpp_add_step(float x) {
  int xi = __builtin_bit_cast(int, x);
  int yi = __builtin_amdgcn_update_dpp(xi, xi, CTRL, 0xF, 0xF, false);
  return x + __builtin_bit_cast(float, yi);
}
__device__ __forceinline__ float row16_max(float v) {
  v = dpp_max_step<0xB1>(v);   // quad_perm [1,0,3,2]  (xor 1)
  v = dpp_max_step<0x4E>(v);   // quad_perm [2,3,0,1]  (xor 2)
  v = dpp_max_step<0x141>(v);  // row_half_mirror      (xor 7)
  v = dpp_max_step<0x140>(v);  // row_mirror           (xor 15)
  return v;
}
__device__ __forceinline__ float row16_sum(float v) {
  v = dpp_add_step<0xB1>(v);
  v = dpp_add_step<0x4E>(v);
  v = dpp_add_step<0x141>(v);
  v = dpp_add_step<0x140>(v);
  return v;
}

// ---------------------------------------------------------------- converts --
__global__ void convert_x(const float* __restrict__ x, bf16* __restrict__ xb) {
  const float4* xv = (const float4*)x;
  int stride = gridDim.x * blockDim.x;
  for (int idx = blockIdx.x * blockDim.x + threadIdx.x; idx < (NTOK * D_) / 4; idx += stride) {
    float4 v = xv[idx];
    bf16x4 o = { (bf16)v.x, (bf16)v.y, (bf16)v.z, (bf16)v.w };
    *(bf16x4*)(xb + (size_t)idx * 4) = o;
  }
}

// W[k][n] f32 -> Wt[n][k] bf16, 4 matrices selected by blockIdx.z
__global__ void wconv(const float* __restrict__ w0, const float* __restrict__ w1,
                      const float* __restrict__ w2, const float* __restrict__ w3,
                      bf16* __restrict__ wt) {
  __shared__ float tile[32][33];
  int z = blockIdx.z;
  const float* W = (z == 0) ? w0 : (z == 1) ? w1 : (z == 2) ? w2 : w3;
  int bx = blockIdx.x, by = blockIdx.y;
  int tx = threadIdx.x, ty = threadIdx.y;
#pragma unroll
  for (int r = 0; r < 32; r += 8)
    tile[ty + r][tx] = W[(size_t)(by * 32 + ty + r) * D_ + bx * 32 + tx];
  __syncthreads();
  bf16* dst = wt + (size_t)z * D_ * D_;
#pragma unroll
  for (int r = 0; r < 32; r += 8)
    dst[(size_t)(bx * 32 + ty + r) * D_ + by * 32 + tx] = (bf16)tile[tx][ty + r];
}

// ------------------------------------------------------------------- GEMM ---
// C(M=8192 x N=1024) = A(row-major, K=1024) * Wt^T   (Wt is [n][k])
// BK=64: 16 K-steps; tiles [128][64] bf16 (128 B rows), chunk swizzle cc^(row&7).
// MODE 0: QKV — z selects weight slice & output; Q/K -> (bh,t,hd) bf16, V -> (bh,hd,t) bf16
// MODE 2: out-proj — fp32 output + bias
template<int MODE>
__global__ __launch_bounds__(256) void gemm128(const bf16* __restrict__ A,
                                               const bf16* __restrict__ Wt,
                                               bf16* __restrict__ outb,
                                               float* __restrict__ outf,
                                               const float* __restrict__ bias) {
  __shared__ __align__(16) bf16 Ash[128 * 64];
  __shared__ __align__(16) bf16 Bsh[128 * 64];
  const int tid = threadIdx.x;
  const int w = tid >> 6, l = tid & 63;
  const int l15 = l & 15, lq = l >> 4;
  const int wr = w >> 1, wc = w & 1;
  const int tm = blockIdx.x, tn = blockIdx.y, z = blockIdx.z;
  const int K = D_;
  const bf16* Bt = Wt + (size_t)z * D_ * D_;

  // staging: 1024 16B chunks per tile; chunk i -> row=i>>3, cc=i&7,
  // source chunk = cc ^ (row&7)  (LDS stays linear; involution on read side)
  const bf16* aSrc[4];
  const bf16* bSrc[4];
  uint32_t sLds[4];
#pragma unroll
  for (int c = 0; c < 4; ++c) {
    int i = (w * 4 + c) * 64 + l;
    int row = i >> 3, cc = i & 7;
    int sc = cc ^ (row & 7);
    aSrc[c] = A + (size_t)(tm * 128 + row) * K + sc * 8;
    bSrc[c] = Bt + (size_t)(tn * 128 + row) * K + sc * 8;
    sLds[c] = (uint32_t)(w * 4 + c) * 1024;
  }
  // fragment read offsets: global chunk g = ks*4+lq of row r -> LDS chunk g^(r&7)
  uint32_t aOff[2][4], bOff[2][4];
#pragma unroll
  for (int ks = 0; ks < 2; ++ks)
#pragma unroll
    for (int m = 0; m < 4; ++m) {
      int ra = wr * 64 + m * 16 + l15;
      aOff[ks][m] = ra * 128 + (((ks * 4 + lq) ^ (ra & 7)) << 4);
      int rb = wc * 64 + m * 16 + l15;
      bOff[ks][m] = rb * 128 + (((ks * 4 + lq) ^ (rb & 7)) << 4);
    }

  f32x4 acc[4][4] = {};
  char* AshB = (char*)Ash;
  char* BshB = (char*)Bsh;

  for (int k0 = 0; k0 < K; k0 += 64) {
    __syncthreads();
#pragma unroll
    for (int c = 0; c < 4; ++c) {
      gload16(aSrc[c], AshB + sLds[c]);
      gload16(bSrc[c], BshB + sLds[c]);
      aSrc[c] += 64;
      bSrc[c] += 64;
    }
    __syncthreads();
#pragma unroll
    for (int ks = 0; ks < 2; ++ks) {
      bf16x8 af[4], bw[4];
#pragma unroll
      for (int m = 0; m < 4; ++m) af[m] = *(const bf16x8*)(AshB + aOff[ks][m]);
#pragma unroll
      for (int n = 0; n < 4; ++n) bw[n] = *(const bf16x8*)(BshB + bOff[ks][n]);
#pragma unroll
      for (int m = 0; m < 4; ++m)
#pragma unroll
        for (int n = 0; n < 4; ++n)
          acc[m][n] = __builtin_amdgcn_mfma_f32_16x16x32_bf16(af[m], bw[n], acc[m][n], 0, 0, 0);
    }
  }

#pragma unroll
  for (int m = 0; m < 4; ++m)
#pragma unroll
    for (int n = 0; n < 4; ++n)
#pragma unroll
      for (int j = 0; j < 4; ++j) {
        int r = tm * 128 + wr * 64 + m * 16 + lq * 4 + j;
        int c = tn * 128 + wc * 64 + n * 16 + l15;
        float v = acc[m][n][j];
        if (MODE == 2) {
          outf[(size_t)r * D_ + c] = v + bias[c];
        } else {
          int b = r >> 11, t = r & (T_ - 1), h = c >> 6, hd = c & 63;
          bf16* dst = outb + (size_t)z * NTOK * D_;
          size_t addr;
          if (z < 2) addr = ((size_t)(b * H_ + h) * T_ + t) * HD_ + hd;   // Q,K: (bh,t,hd)
          else       addr = ((size_t)(b * H_ + h) * HD_ + hd) * T_ + t;   // V: (bh,hd,t)
          dst[addr] = (bf16)v;
        }
      }
}

// ------------------------------------------------------------- attention ---
// grid (8, bh=64), 256 thr = 4 waves. Each block runs TWO q-tiles sequentially:
// qt = 15-bx then qt = bx  -> 34 KV-tiles per block, perfectly balanced.
// Per pass: double-buffered K/V, counted vmcnt, DPP softmax (no LDS shuffles).
__global__ __launch_bounds__(256) void attn(const bf16* __restrict__ Q,
                                            const bf16* __restrict__ Kg,
                                            const bf16* __restrict__ Vg,
                                            bf16* __restrict__ ctx) {
  __shared__ __align__(16) bf16 Ksh[2][64 * 64];   // [buf][kv][hd], chunk-swizzled
  __shared__ __align__(16) bf16 Vsh[2][64 * 64];   // [buf][hd][kv], chunk-swizzled
  __shared__ __align__(16) bf16 Psh[4 * 32 * 64];  // per-wave [q][kv], swizzled
  const int tid = threadIdx.x;
  const int w = tid >> 6, l = tid & 63;
  const int l15 = l & 15, lq = l >> 4;
  const int bx = blockIdx.x, bh = blockIdx.y;

  char* KshB = (char*)Ksh;
  char* VshB = (char*)Vsh;
  char* PshB = (char*)Psh;

  // staging lane->(row, chunk) with source-side swizzle (LDS dest stays linear)
  uint32_t stRow[2], stCol[2], sLds[2];
#pragma unroll
  for (int c = 0; c < 2; ++c) {
    int i = (w * 2 + c) * 64 + l;
    int row = i >> 3, cc = i & 7;
    stRow[c] = row;
    stCol[c] = (cc ^ (row & 7)) * 8;
    sLds[c] = (uint32_t)(w * 2 + c) * 1024;
  }
  uint32_t kOff[2][4], pOff[2][2];
#pragma unroll
  for (int ks = 0; ks < 2; ++ks) {
#pragma unroll
    for (int n = 0; n < 4; ++n) {
      int row = n * 16 + l15, c = ks * 4 + lq;
      kOff[ks][n] = row * 128 + ((c ^ (row & 7)) << 4);
    }
#pragma unroll
    for (int m = 0; m < 2; ++m) {
      int row = m * 16 + l15, c = ks * 4 + lq;
      pOff[ks][m] = w * 4096 + row * 128 + ((c ^ (row & 7)) << 4);
    }
  }
  const uint32_t h16 = (uint32_t)(l & 8) << 1;   // (l15>>3)<<4
  const uint32_t pb0 = w * 4096u + ((uint32_t)(l & 7) << 1);

  const int b = bh >> 4, h = bh & 15;

  for (int pass = 0; pass < 2; ++pass) {
    const int qt = pass ? bx : 15 - bx;
    const int qbase = qt * 128 + w * 32;
    const int kvmax = 2 * qt + 2;

    // Q fragments for this pass
    bf16x8 qf[2][2];
#pragma unroll
    for (int m = 0; m < 2; ++m)
#pragma unroll
      for (int ks = 0; ks < 2; ++ks)
        qf[m][ks] = *(const bf16x8*)(Q + ((size_t)bh * T_ + qbase + m * 16 + l15) * HD_ + ks * 32 + lq * 8);
    // force Q resident now so its waitcnt doesn't fold into the loop
#pragma unroll
    for (int m = 0; m < 2; ++m)
#pragma unroll
      for (int ks = 0; ks < 2; ++ks)
        asm volatile("" : "+v"(qf[m][ks]));

    f32x4 acc_o[2][4] = {};
    float mr[2][4], lr[2][4];
#pragma unroll
    for (int m = 0; m < 2; ++m)
#pragma unroll
      for (int j = 0; j < 4; ++j) { mr[m][j] = -__builtin_inff(); lr[m][j] = 0.f; }

    const bf16* kSrc[2];
    const bf16* vSrc[2];
#pragma unroll
    for (int c = 0; c < 2; ++c) {
      kSrc[c] = Kg + ((size_t)bh * T_ + stRow[c]) * HD_ + stCol[c];
      vSrc[c] = Vg + ((size_t)bh * HD_ + stRow[c]) * T_ + stCol[c];
    }

    // prologue: stage tile 0 into buffer 0
#pragma unroll
    for (int c = 0; c < 2; ++c) {
      gload16(kSrc[c], KshB + sLds[c]);
      gload16(vSrc[c], VshB + sLds[c]);
      kSrc[c] += 64 * HD_;
      vSrc[c] += 64;
    }

    for (int kvt = 0; kvt < kvmax; ++kvt) {
      const uint32_t cb = (uint32_t)(kvt & 1) * 8192;
      const uint32_t nb = cb ^ 8192;
      const bool pre = (kvt + 1) < kvmax;
      if (pre) {
#pragma unroll
        for (int c = 0; c < 2; ++c) {
          gload16(kSrc[c], KshB + nb + sLds[c]);
          gload16(vSrc[c], VshB + nb + sLds[c]);
          kSrc[c] += 64 * HD_;
          vSrc[c] += 64;
        }
        asm volatile("s_waitcnt vmcnt(4)" ::: "memory");
      } else {
        asm volatile("s_waitcnt vmcnt(0)" ::: "memory");
      }
      __builtin_amdgcn_sched_barrier(0);
      __builtin_amdgcn_s_barrier();
      __builtin_amdgcn_sched_barrier(0);

      const bool active = (kvt * 64) <= (qbase + 31);
      if (active) {
        // S = Q K^T (raw scores; scale folded into exp2 args)
        f32x4 accs[2][4] = {};
        __builtin_amdgcn_s_setprio(1);
#pragma unroll
        for (int ks = 0; ks < 2; ++ks) {
          bf16x8 kf[4];
#pragma unroll
          for (int n = 0; n < 4; ++n) kf[n] = *(const bf16x8*)(KshB + cb + kOff[ks][n]);
#pragma unroll
          for (int m = 0; m < 2; ++m)
#pragma unroll
            for (int n = 0; n < 4; ++n)
              accs[m][n] = __builtin_amdgcn_mfma_f32_16x16x32_bf16(qf[m][ks], kf[n], accs[m][n], 0, 0, 0);
        }
        __builtin_amdgcn_s_setprio(0);

        const bool needmask = (kvt * 64 + 63) > qbase;
        if (needmask) {
#pragma unroll
          for (int m = 0; m < 2; ++m)
#pragma unroll
            for (int n = 0; n < 4; ++n) {
              int kv = kvt * 64 + n * 16 + l15;
#pragma unroll
              for (int j = 0; j < 4; ++j) {
                int q = qbase + m * 16 + lq * 4 + j;
                if (kv > q) accs[m][n][j] = -__builtin_inff();
              }
            }
        }

        // online softmax: DPP 16-lane reductions, all-VALU
#pragma unroll
        for (int m = 0; m < 2; ++m)
#pragma unroll
          for (int j = 0; j < 4; ++j) {
            float v = fmaxf(fmaxf(accs[m][0][j], accs[m][1][j]),
                            fmaxf(accs[m][2][j], accs[m][3][j]));
            v = row16_max(v);
            float mn = fmaxf(mr[m][j], v);                 // raw-units running max
            float r = EXP2((mr[m][j] - mn) * SCL);
            mr[m][j] = mn;
            float nm = -mn * SCL;
            int rowP = m * 16 + lq * 4 + j;
            uint32_t pb = pb0 + (uint32_t)rowP * 128u;
            uint32_t px = (uint32_t)(rowP & 7) << 4;
            float rs = 0.f;
#pragma unroll
            for (int n = 0; n < 4; ++n) {
              float p = EXP2(__builtin_fmaf(accs[m][n][j], SCL, nm));
              rs += p;
              *(bf16*)(PshB + pb + (((uint32_t)n * 32u + h16) ^ px)) = (bf16)p;
            }
            rs = row16_sum(rs);
            lr[m][j] = lr[m][j] * r + rs;
#pragma unroll
            for (int n = 0; n < 4; ++n) acc_o[m][n][j] *= r;
          }

        asm volatile("s_waitcnt lgkmcnt(0)" ::: "memory");
        __builtin_amdgcn_sched_barrier(0);

        // O += P V (P per-wave private in LDS)
        __builtin_amdgcn_s_setprio(1);
#pragma unroll
        for (int ks = 0; ks < 2; ++ks) {
          bf16x8 pf[2], vf[4];
#pragma unroll
          for (int m = 0; m < 2; ++m) pf[m] = *(const bf16x8*)(PshB + pOff[ks][m]);
#pragma unroll
          for (int n = 0; n < 4; ++n) vf[n] = *(const bf16x8*)(VshB + cb + kOff[ks][n]);
#pragma unroll
          for (int m = 0; m < 2; ++m)
#pragma unroll
            for (int n = 0; n < 4; ++n)
              acc_o[m][n] = __builtin_amdgcn_mfma_f32_16x16x32_bf16(pf[m], vf[n], acc_o[m][n], 0, 0, 0);
        }
        __builtin_amdgcn_s_setprio(0);
      }
      // all waves done reading buf[cb] before it is re-staged
      __builtin_amdgcn_s_barrier();
    }

    // epilogue for this pass
#pragma unroll
    for (int m = 0; m < 2; ++m)
#pragma unroll
      for (int n = 0; n < 4; ++n)
#pragma unroll
        for (int j = 0; j < 4; ++j) {
          int t = qbase + m * 16 + lq * 4 + j;
          int c = h * 64 + n * 16 + l15;
          float v = acc_o[m][n][j] / lr[m][j];
          ctx[((size_t)b * T_ + t) * D_ + c] = (bf16)v;
        }
  }
}

// ----------------------------------------------------------------- launch ---
extern "C" void kernel_launch(void* const* d_in, const int* in_sizes, int n_in,
                              void* d_out, int out_size, void* d_ws, size_t ws_size,
                              hipStream_t stream) {
  const float* x  = (const float*)d_in[0];
  const float* Wq = (const float*)d_in[1];
  const float* Wk = (const float*)d_in[2];
  const float* Wv = (const float*)d_in[3];
  const float* Wo = (const float*)d_in[4];
  const float* bo = (const float*)d_in[5];
  float* out = (float*)d_out;

  bf16* ws  = (bf16*)d_ws;
  bf16* xb  = ws;                                   //  8M elems: x bf16
  bf16* wt  = ws + (size_t)8 * 1024 * 1024;         //  4M elems: Wq^T,Wk^T,Wv^T,Wo^T
  bf16* qkv = ws + (size_t)12 * 1024 * 1024;        // 24M elems: Q, K, Vt
  bf16* ctx = ws + (size_t)36 * 1024 * 1024;        //  8M elems: attn output
  // total 44M bf16 = 88 MB

  convert_x<<<2048, 256, 0, stream>>>(x, xb);
  wconv<<<dim3(32, 32, 4), dim3(32, 8), 0, stream>>>(Wq, Wk, Wv, Wo, wt);
  gemm128<0><<<dim3(64, 8, 3), 256, 0, stream>>>(xb, wt, qkv, nullptr, nullptr);
  attn<<<dim3(8, 64), 256, 0, stream>>>(qkv, qkv + (size_t)8 * 1024 * 1024,
                                        qkv + (size_t)16 * 1024 * 1024, ctx);
  gemm128<2><<<dim3(64, 8, 1), 256, 0, stream>>>(ctx, wt + (size_t)3 * 1024 * 1024,
                                                 nullptr, out, bo);
}